// Round 1
// baseline (1865.405 us; speedup 1.0000x reference)
//
#include <hip/hip_runtime.h>
#include <cstddef>

// Problem constants (from reference):
#define L_SEQ  2048
#define B_SZ   2
#define E_DIM  1024
#define H_N    16
#define D_HEAD 64
#define R_DIM  256

// ---------------------------------------------------------------------------
// Generic fp32 tiled GEMM:  C = alpha * A @ op(B) + beta * C + bias
//   A: [M,K] row-major, leading dim lda
//   B: TRANSB ? [N,K] (we compute A @ B^T) : [K,N], leading dim ldb
//   C: [M,N] leading dim ldc
// Batch via blockIdx.z. Per-operand offset mode:
//   mode 0: off = z * stride
//   mode 1: off = (z / H_N) * E_DIM + (z % H_N) * D_HEAD   (head-sliced [L,B,H,D] view)
// All M,N multiples of 64 and K multiples of 16 in this problem -> no guards.
// All base pointers / strides are multiples of 4 floats -> float4 loads legal.
// LDS layout: K-major with +4 pad (68) so compute reads are ds_read_b128;
// transposed scatter-writes are 2-way bank aliased (free on gfx950, m136).
// ---------------------------------------------------------------------------
template <bool TRANSB>
__global__ __launch_bounds__(256)
void gemm_tiled(float* __restrict__ Cb, const float* __restrict__ Ab,
                const float* __restrict__ Bb, const float* __restrict__ bias,
                int M, int N, int K, int lda, int ldb, int ldc,
                long aStride, int aMode, long bStride, int bMode,
                long cStride, int cMode, float alpha, float beta)
{
    __shared__ float As[16][68];
    __shared__ float Bs[16][68];

    const int z = blockIdx.z;
    const long headOff = (long)(z / H_N) * E_DIM + (long)(z % H_N) * D_HEAD;
    const long aOff = (aMode == 1) ? headOff : (long)z * aStride;
    const long bOff = (bMode == 1) ? headOff : (long)z * bStride;
    const long cOff = (cMode == 1) ? headOff : (long)z * cStride;

    const float* A  = Ab + aOff;
    const float* Bp = Bb + bOff;
    float*       C  = Cb + cOff;

    const int tid = threadIdx.x;       // 256 threads
    const int tx  = tid & 15;
    const int ty  = tid >> 4;
    const int tm  = blockIdx.y * 64;
    const int tn  = blockIdx.x * 64;

    // cooperative-load indices
    const int arow = tid >> 2;         // 0..63 (row within 64-tile)
    const int ak   = (tid & 3) << 2;   // 0,4,8,12 (k within 16-panel)
    const int brow = tid >> 4;         // 0..15  (k, NN path)
    const int bcol = (tid & 15) << 2;  // 0..60  (n, NN path)

    float acc[4][4] = {};

    for (int k0 = 0; k0 < K; k0 += 16) {
        // ---- stage A panel (transpose to K-major) ----
        float4 av = *(const float4*)(A + (long)(tm + arow) * lda + (k0 + ak));
        As[ak + 0][arow] = av.x;
        As[ak + 1][arow] = av.y;
        As[ak + 2][arow] = av.z;
        As[ak + 3][arow] = av.w;
        // ---- stage B panel ----
        if (TRANSB) {
            float4 bv = *(const float4*)(Bp + (long)(tn + arow) * ldb + (k0 + ak));
            Bs[ak + 0][arow] = bv.x;
            Bs[ak + 1][arow] = bv.y;
            Bs[ak + 2][arow] = bv.z;
            Bs[ak + 3][arow] = bv.w;
        } else {
            float4 bv = *(const float4*)(Bp + (long)(k0 + brow) * ldb + (tn + bcol));
            *(float4*)&Bs[brow][bcol] = bv;   // row base 68*4B and bcol*4B are 16B-aligned
        }
        __syncthreads();

        #pragma unroll
        for (int kk = 0; kk < 16; kk++) {
            float4 a4 = *(const float4*)&As[kk][ty << 2];
            float4 b4 = *(const float4*)&Bs[kk][tx << 2];
            const float ar[4] = {a4.x, a4.y, a4.z, a4.w};
            const float br[4] = {b4.x, b4.y, b4.z, b4.w};
            #pragma unroll
            for (int i = 0; i < 4; i++)
                #pragma unroll
                for (int j = 0; j < 4; j++)
                    acc[i][j] = fmaf(ar[i], br[j], acc[i][j]);
        }
        __syncthreads();
    }

    // ---- epilogue ----
    #pragma unroll
    for (int i = 0; i < 4; i++) {
        const int row = tm + (ty << 2) + i;
        const int col = tn + (tx << 2);
        float* cp = C + (long)row * ldc + col;
        float4 cv;
        cv.x = alpha * acc[i][0];
        cv.y = alpha * acc[i][1];
        cv.z = alpha * acc[i][2];
        cv.w = alpha * acc[i][3];
        if (beta != 0.0f) {
            float4 o = *(const float4*)cp;
            cv.x += beta * o.x; cv.y += beta * o.y;
            cv.z += beta * o.z; cv.w += beta * o.w;
        }
        if (bias) {
            cv.x += bias[col + 0]; cv.y += bias[col + 1];
            cv.z += bias[col + 2]; cv.w += bias[col + 3];
        }
        *(float4*)cp = cv;
    }
}

// ---------------------------------------------------------------------------
// Row softmax in place over the attention score matrix.
// attn: [B*H, L, L] contiguous; mask: [L, L], broadcast over (b,h).
// One block (256 threads) per row of length L_SEQ=2048 -> 8 elems/thread.
// ---------------------------------------------------------------------------
__global__ __launch_bounds__(256)
void softmax_rows(float* __restrict__ attn, const float* __restrict__ mask)
{
    const int l  = blockIdx.x & (L_SEQ - 1);
    const int bh = blockIdx.x >> 11;          // L_SEQ = 2^11
    float* row        = attn + ((size_t)bh * L_SEQ + l) * L_SEQ;
    const float* mrow = mask + (size_t)l * L_SEQ;

    const int tid  = threadIdx.x;
    const int wave = tid >> 6;
    const int lane = tid & 63;

    float v[8];
    float mx = -3.4e38f;
    #pragma unroll
    for (int i = 0; i < 8; i++) {
        const int idx = tid + i * 256;
        v[i] = row[idx] + mrow[idx];
        mx = fmaxf(mx, v[i]);
    }
    #pragma unroll
    for (int off = 32; off >= 1; off >>= 1)
        mx = fmaxf(mx, __shfl_xor(mx, off, 64));

    __shared__ float sred[4];
    if (lane == 0) sred[wave] = mx;
    __syncthreads();
    mx = fmaxf(fmaxf(sred[0], sred[1]), fmaxf(sred[2], sred[3]));

    float sum = 0.0f;
    #pragma unroll
    for (int i = 0; i < 8; i++) {
        v[i] = __expf(v[i] - mx);
        sum += v[i];
    }
    #pragma unroll
    for (int off = 32; off >= 1; off >>= 1)
        sum += __shfl_xor(sum, off, 64);

    __syncthreads();                 // protect sred reuse
    if (lane == 0) sred[wave] = sum;
    __syncthreads();
    const float total = sred[0] + sred[1] + sred[2] + sred[3];
    const float inv = 1.0f / total;

    #pragma unroll
    for (int i = 0; i < 8; i++)
        row[tid + i * 256] = v[i] * inv;
}

// ---------------------------------------------------------------------------
extern "C" void kernel_launch(void* const* d_in, const int* in_sizes, int n_in,
                              void* d_out, int out_size, void* d_ws, size_t ws_size,
                              hipStream_t stream)
{
    const float* x    = (const float*)d_in[0];
    const float* mask = (const float*)d_in[1];
    const float* Wq   = (const float*)d_in[2];
    const float* bq   = (const float*)d_in[3];
    const float* Wk   = (const float*)d_in[4];
    const float* bk   = (const float*)d_in[5];
    const float* Wv   = (const float*)d_in[6];
    const float* bv   = (const float*)d_in[7];
    const float* Wo   = (const float*)d_in[8];
    const float* bo   = (const float*)d_in[9];
    const float* U    = (const float*)d_in[10];

    float* out  = (float*)d_out;                                  // [L,B,E]
    float* attn = out + (size_t)L_SEQ * B_SZ * E_DIM;             // [B,H,L,L]

    // workspace layout (fp32): Q | K | V | P   (52 MB total)
    const size_t SZ_LBE = (size_t)L_SEQ * B_SZ * E_DIM;           // 4,194,304
    float* Qb  = (float*)d_ws;
    float* Kb  = Qb + SZ_LBE;
    float* Vb  = Kb + SZ_LBE;
    float* Pb  = Vb + SZ_LBE;                                     // [4096, 256]
    float* ctx = Qb;  // reuse Q region after QK^T has consumed Qc

    const dim3 blk(256);
    const int M  = L_SEQ * B_SZ;  // 4096

    // 1-3. Q/K/V projections: [4096,1024] = x @ W^T + b
    {
        dim3 g(E_DIM / 64, M / 64, 1);
        hipLaunchKernelGGL((gemm_tiled<true>), g, blk, 0, stream,
            Qb, x, Wq, bq, M, E_DIM, E_DIM, E_DIM, E_DIM, E_DIM,
            0, 0, 0, 0, 0, 0, 1.0f, 0.0f);
        hipLaunchKernelGGL((gemm_tiled<true>), g, blk, 0, stream,
            Kb, x, Wk, bk, M, E_DIM, E_DIM, E_DIM, E_DIM, E_DIM,
            0, 0, 0, 0, 0, 0, 1.0f, 0.0f);
        hipLaunchKernelGGL((gemm_tiled<true>), g, blk, 0, stream,
            Vb, x, Wv, bv, M, E_DIM, E_DIM, E_DIM, E_DIM, E_DIM,
            0, 0, 0, 0, 0, 0, 1.0f, 0.0f);
    }

    // 4-5. Condition Q:  P = Q @ U ; Q = 0.4 * P @ U^T + 0.6 * Q  (in place)
    {
        dim3 gp(R_DIM / 64, M / 64, 1);
        hipLaunchKernelGGL((gemm_tiled<false>), gp, blk, 0, stream,
            Pb, Qb, U, (const float*)nullptr, M, R_DIM, E_DIM, E_DIM, R_DIM, R_DIM,
            0, 0, 0, 0, 0, 0, 1.0f, 0.0f);
        dim3 gc(E_DIM / 64, M / 64, 1);
        hipLaunchKernelGGL((gemm_tiled<true>), gc, blk, 0, stream,
            Qb, Pb, U, (const float*)nullptr, M, E_DIM, R_DIM, R_DIM, R_DIM, E_DIM,
            0, 0, 0, 0, 0, 0, 0.4f, 0.6f);
        // Condition K likewise
        hipLaunchKernelGGL((gemm_tiled<false>), gp, blk, 0, stream,
            Pb, Kb, U, (const float*)nullptr, M, R_DIM, E_DIM, E_DIM, R_DIM, R_DIM,
            0, 0, 0, 0, 0, 0, 1.0f, 0.0f);
        hipLaunchKernelGGL((gemm_tiled<true>), gc, blk, 0, stream,
            Kb, Pb, U, (const float*)nullptr, M, E_DIM, R_DIM, R_DIM, R_DIM, E_DIM,
            0, 0, 0, 0, 0, 0, 0.4f, 0.6f);
    }

    // 7. Scores: per (b,h): attn = (q @ k^T) / 8   -> straight into d_out attn region
    {
        dim3 g(L_SEQ / 64, L_SEQ / 64, B_SZ * H_N);
        hipLaunchKernelGGL((gemm_tiled<true>), g, blk, 0, stream,
            attn, Qb, Kb, (const float*)nullptr,
            L_SEQ, L_SEQ, D_HEAD, B_SZ * E_DIM, B_SZ * E_DIM, L_SEQ,
            0, 1, 0, 1, (long)L_SEQ * L_SEQ, 0, 0.125f, 0.0f);
    }

    // 8. softmax(scores + mask) in place
    hipLaunchKernelGGL(softmax_rows, dim3(B_SZ * H_N * L_SEQ), blk, 0, stream,
                       attn, mask);

    // 9. ctx = attn @ v  -> head-sliced [L,B,E] (reuses Q region)
    {
        dim3 g(D_HEAD / 64, L_SEQ / 64, B_SZ * H_N);
        hipLaunchKernelGGL((gemm_tiled<false>), g, blk, 0, stream,
            ctx, attn, Vb, (const float*)nullptr,
            L_SEQ, D_HEAD, L_SEQ, L_SEQ, B_SZ * E_DIM, B_SZ * E_DIM,
            (long)L_SEQ * L_SEQ, 0, 0, 1, 0, 1, 1.0f, 0.0f);
    }

    // 10. out = ctx @ Wo^T + bo
    {
        dim3 g(E_DIM / 64, M / 64, 1);
        hipLaunchKernelGGL((gemm_tiled<true>), g, blk, 0, stream,
            out, ctx, Wo, bo, M, E_DIM, E_DIM, E_DIM, E_DIM, E_DIM,
            0, 0, 0, 0, 0, 0, 1.0f, 0.0f);
    }
}